// Round 1
// baseline (557.417 us; speedup 1.0000x reference)
//
#include <hip/hip_runtime.h>
#include <hip/hip_bf16.h>

#define T_TOK 2048
#define HID 1024
#define FFNDIM 2048
#define NEXP 8

typedef __attribute__((ext_vector_type(8))) short short8;
typedef __attribute__((ext_vector_type(4))) float f32x4;

__device__ inline unsigned short f2bf(float f) {
  union { float f; unsigned int u; } v; v.f = f;
  unsigned int u = v.u;
  unsigned int r = (u + 0x7fffu + ((u >> 16) & 1u)) >> 16;
  return (unsigned short)r;
}

// ---------------- router: 1 wave per token ----------------
__global__ __launch_bounds__(256) void router_kernel(
    const float* __restrict__ x, const float* __restrict__ gw,
    int* __restrict__ counts, int* __restrict__ top_i, float* __restrict__ top_w) {
  int lane = threadIdx.x & 63;
  int t = blockIdx.x * 4 + (threadIdx.x >> 6);
  if (t >= T_TOK) return;
  float xv[16];
#pragma unroll
  for (int i = 0; i < 16; ++i) xv[i] = x[(size_t)t * HID + i * 64 + lane];
  float logit[NEXP];
#pragma unroll
  for (int e = 0; e < NEXP; ++e) {
    float s = 0.f;
#pragma unroll
    for (int i = 0; i < 16; ++i) s += xv[i] * gw[e * HID + i * 64 + lane];
#pragma unroll
    for (int off = 32; off > 0; off >>= 1) s += __shfl_xor(s, off);
    logit[e] = s;
  }
  if (lane == 0) {
    float mx = logit[0];
#pragma unroll
    for (int e = 1; e < NEXP; ++e) mx = fmaxf(mx, logit[e]);
    float p[NEXP]; float sum = 0.f;
#pragma unroll
    for (int e = 0; e < NEXP; ++e) { p[e] = expf(logit[e] - mx); sum += p[e]; }
#pragma unroll
    for (int e = 0; e < NEXP; ++e) p[e] /= sum;
    // top-2, lowest index wins ties (matches jax.lax.top_k)
    int i0 = 0;
#pragma unroll
    for (int e = 1; e < NEXP; ++e) if (p[e] > p[i0]) i0 = e;
    int i1 = (i0 == 0) ? 1 : 0;
#pragma unroll
    for (int e = 0; e < NEXP; ++e) if (e != i0 && p[e] > p[i1]) i1 = e;
    float w0 = p[i0], w1v = p[i1];
    float s2 = w0 + w1v;
    w0 /= s2; w1v /= s2;
    top_i[t * 2 + 0] = i0; top_i[t * 2 + 1] = i1;
    top_w[t * 2 + 0] = w0; top_w[t * 2 + 1] = w1v;
    atomicAdd(&counts[i0], 1);
    atomicAdd(&counts[i1], 1);
  }
}

// ---------------- offsets: tiny prefix sum ----------------
__global__ void offsets_kernel(const int* __restrict__ counts, int* __restrict__ offsets) {
  if (threadIdx.x == 0 && blockIdx.x == 0) {
    int s = 0;
    for (int e = 0; e < NEXP; ++e) { offsets[e] = s; s += counts[e]; }
    offsets[NEXP] = s;
  }
}

// ---------------- scatter token->expert-row lists ----------------
__global__ __launch_bounds__(256) void scatter_kernel(
    const int* __restrict__ top_i, const float* __restrict__ top_w,
    const int* __restrict__ offsets, int* __restrict__ cursor,
    int* __restrict__ row_tok, float* __restrict__ row_w) {
  int t = blockIdx.x * 256 + threadIdx.x;
  if (t >= T_TOK) return;
#pragma unroll
  for (int k = 0; k < 2; ++k) {
    int e = top_i[t * 2 + k];
    int p = atomicAdd(&cursor[e], 1);
    int idx = offsets[e] + p;
    row_tok[idx] = t;
    row_w[idx] = top_w[t * 2 + k];
  }
}

// ---------------- gather x rows -> bf16 ----------------
__global__ __launch_bounds__(256) void gather_kernel(
    const float* __restrict__ x, const int* __restrict__ row_tok,
    unsigned short* __restrict__ Xg) {
  int r = blockIdx.x;
  int t = row_tok[r];
  int c = threadIdx.x * 4;
  float4 v = *reinterpret_cast<const float4*>(x + (size_t)t * HID + c);
  ushort4 o;
  o.x = f2bf(v.x); o.y = f2bf(v.y); o.z = f2bf(v.z); o.w = f2bf(v.w);
  *reinterpret_cast<ushort4*>(Xg + (size_t)r * HID + c) = o;
}

// ---------------- GEMM1: h = silu(Xg@w1^T) * (Xg@w3^T), per expert ----------------
__global__ __launch_bounds__(256) void gemm1_kernel(
    const unsigned short* __restrict__ Xg,
    const float* __restrict__ w1, const float* __restrict__ w3,
    const int* __restrict__ counts, const int* __restrict__ offsets,
    unsigned short* __restrict__ hbuf) {
  int e = blockIdx.z;
  int cnt = counts[e];
  int mt = blockIdx.x, nt = blockIdx.y;
  if (mt * 64 >= cnt) return;
  int off = offsets[e];

  __shared__ alignas(16) unsigned short sA[64 * 32];
  __shared__ alignas(16) unsigned short sB1[64 * 32];
  __shared__ alignas(16) unsigned short sB3[64 * 32];

  int tid = threadIdx.x;
  int lane = tid & 63, wid = tid >> 6;
  int wm = wid >> 1, wn = wid & 1;

  f32x4 acc1[2][2], acc3[2][2];
#pragma unroll
  for (int m = 0; m < 2; ++m)
#pragma unroll
    for (int n = 0; n < 2; ++n) {
      acc1[m][n] = (f32x4){0.f, 0.f, 0.f, 0.f};
      acc3[m][n] = (f32x4){0.f, 0.f, 0.f, 0.f};
    }

  int srow = tid >> 2;        // 0..63
  int skc = (tid & 3) * 8;    // 0,8,16,24
  int gmS = mt * 64 + srow;
  bool aval = gmS < cnt;
  const unsigned short* ap = Xg + (size_t)(off + (aval ? gmS : 0)) * HID + skc;
  const float* w1p = w1 + (size_t)e * FFNDIM * HID + (size_t)(nt * 64 + srow) * HID + skc;
  const float* w3p = w3 + (size_t)e * FFNDIM * HID + (size_t)(nt * 64 + srow) * HID + skc;

  int fr = lane & 15, fq = lane >> 4;   // fragment row/col + k-group

  for (int k0 = 0; k0 < HID; k0 += 32) {
    __syncthreads();
    short8 av = {0, 0, 0, 0, 0, 0, 0, 0};
    if (aval) av = *reinterpret_cast<const short8*>(ap + k0);
    *reinterpret_cast<short8*>(&sA[srow * 32 + skc]) = av;

    float4 b0 = *reinterpret_cast<const float4*>(w1p + k0);
    float4 b1 = *reinterpret_cast<const float4*>(w1p + k0 + 4);
    short8 bv;
    bv[0] = (short)f2bf(b0.x); bv[1] = (short)f2bf(b0.y);
    bv[2] = (short)f2bf(b0.z); bv[3] = (short)f2bf(b0.w);
    bv[4] = (short)f2bf(b1.x); bv[5] = (short)f2bf(b1.y);
    bv[6] = (short)f2bf(b1.z); bv[7] = (short)f2bf(b1.w);
    *reinterpret_cast<short8*>(&sB1[srow * 32 + skc]) = bv;

    float4 c0 = *reinterpret_cast<const float4*>(w3p + k0);
    float4 c1 = *reinterpret_cast<const float4*>(w3p + k0 + 4);
    short8 cv;
    cv[0] = (short)f2bf(c0.x); cv[1] = (short)f2bf(c0.y);
    cv[2] = (short)f2bf(c0.z); cv[3] = (short)f2bf(c0.w);
    cv[4] = (short)f2bf(c1.x); cv[5] = (short)f2bf(c1.y);
    cv[6] = (short)f2bf(c1.z); cv[7] = (short)f2bf(c1.w);
    *reinterpret_cast<short8*>(&sB3[srow * 32 + skc]) = cv;
    __syncthreads();

    short8 a[2], f1[2], f3[2];
#pragma unroll
    for (int m = 0; m < 2; ++m)
      a[m] = *reinterpret_cast<const short8*>(&sA[(wm * 32 + m * 16 + fr) * 32 + fq * 8]);
#pragma unroll
    for (int n = 0; n < 2; ++n) {
      f1[n] = *reinterpret_cast<const short8*>(&sB1[(wn * 32 + n * 16 + fr) * 32 + fq * 8]);
      f3[n] = *reinterpret_cast<const short8*>(&sB3[(wn * 32 + n * 16 + fr) * 32 + fq * 8]);
    }
#pragma unroll
    for (int m = 0; m < 2; ++m)
#pragma unroll
      for (int n = 0; n < 2; ++n) {
        acc1[m][n] = __builtin_amdgcn_mfma_f32_16x16x32_bf16(a[m], f1[n], acc1[m][n], 0, 0, 0);
        acc3[m][n] = __builtin_amdgcn_mfma_f32_16x16x32_bf16(a[m], f3[n], acc3[m][n], 0, 0, 0);
      }
  }

  // epilogue: silu(h1)*h3 -> bf16 hbuf
#pragma unroll
  for (int m = 0; m < 2; ++m) {
    int rl = wm * 32 + m * 16 + fq * 4;
#pragma unroll
    for (int j = 0; j < 4; ++j) {
      int gm = mt * 64 + rl + j;
      if (gm < cnt) {
#pragma unroll
        for (int n = 0; n < 2; ++n) {
          float h1 = acc1[m][n][j], h3 = acc3[m][n][j];
          float sv = h1 / (1.f + expf(-h1)) * h3;
          int gn = nt * 64 + wn * 32 + n * 16 + fr;
          hbuf[(size_t)(off + gm) * FFNDIM + gn] = f2bf(sv);
        }
      }
    }
  }
}

// ---------------- GEMM2: out += rw * (h @ w2^T), scatter-add ----------------
__global__ __launch_bounds__(256) void gemm2_kernel(
    const unsigned short* __restrict__ hbuf, const float* __restrict__ w2,
    const int* __restrict__ counts, const int* __restrict__ offsets,
    const int* __restrict__ row_tok, const float* __restrict__ row_w,
    float* __restrict__ out) {
  int e = blockIdx.z;
  int cnt = counts[e];
  int mt = blockIdx.x, nt = blockIdx.y;
  if (mt * 64 >= cnt) return;
  int off = offsets[e];

  __shared__ alignas(16) unsigned short sA[64 * 32];
  __shared__ alignas(16) unsigned short sB[64 * 32];

  int tid = threadIdx.x;
  int lane = tid & 63, wid = tid >> 6;
  int wm = wid >> 1, wn = wid & 1;

  f32x4 acc[2][2];
#pragma unroll
  for (int m = 0; m < 2; ++m)
#pragma unroll
    for (int n = 0; n < 2; ++n) acc[m][n] = (f32x4){0.f, 0.f, 0.f, 0.f};

  int srow = tid >> 2;
  int skc = (tid & 3) * 8;
  int gmS = mt * 64 + srow;
  bool aval = gmS < cnt;
  const unsigned short* ap = hbuf + (size_t)(off + (aval ? gmS : 0)) * FFNDIM + skc;
  const float* w2p = w2 + (size_t)e * HID * FFNDIM + (size_t)(nt * 64 + srow) * FFNDIM + skc;

  int fr = lane & 15, fq = lane >> 4;

  for (int k0 = 0; k0 < FFNDIM; k0 += 32) {
    __syncthreads();
    short8 av = {0, 0, 0, 0, 0, 0, 0, 0};
    if (aval) av = *reinterpret_cast<const short8*>(ap + k0);
    *reinterpret_cast<short8*>(&sA[srow * 32 + skc]) = av;

    float4 b0 = *reinterpret_cast<const float4*>(w2p + k0);
    float4 b1 = *reinterpret_cast<const float4*>(w2p + k0 + 4);
    short8 bv;
    bv[0] = (short)f2bf(b0.x); bv[1] = (short)f2bf(b0.y);
    bv[2] = (short)f2bf(b0.z); bv[3] = (short)f2bf(b0.w);
    bv[4] = (short)f2bf(b1.x); bv[5] = (short)f2bf(b1.y);
    bv[6] = (short)f2bf(b1.z); bv[7] = (short)f2bf(b1.w);
    *reinterpret_cast<short8*>(&sB[srow * 32 + skc]) = bv;
    __syncthreads();

    short8 a[2], b[2];
#pragma unroll
    for (int m = 0; m < 2; ++m)
      a[m] = *reinterpret_cast<const short8*>(&sA[(wm * 32 + m * 16 + fr) * 32 + fq * 8]);
#pragma unroll
    for (int n = 0; n < 2; ++n)
      b[n] = *reinterpret_cast<const short8*>(&sB[(wn * 32 + n * 16 + fr) * 32 + fq * 8]);
#pragma unroll
    for (int m = 0; m < 2; ++m)
#pragma unroll
      for (int n = 0; n < 2; ++n)
        acc[m][n] = __builtin_amdgcn_mfma_f32_16x16x32_bf16(a[m], b[n], acc[m][n], 0, 0, 0);
  }

#pragma unroll
  for (int m = 0; m < 2; ++m) {
    int rl = wm * 32 + m * 16 + fq * 4;
#pragma unroll
    for (int j = 0; j < 4; ++j) {
      int gm = mt * 64 + rl + j;
      if (gm < cnt) {
        int t = row_tok[off + gm];
        float rw = row_w[off + gm];
#pragma unroll
        for (int n = 0; n < 2; ++n) {
          int gn = nt * 64 + wn * 32 + n * 16 + fr;
          atomicAdd(&out[(size_t)t * HID + gn], acc[m][n][j] * rw);
        }
      }
    }
  }
}

extern "C" void kernel_launch(void* const* d_in, const int* in_sizes, int n_in,
                              void* d_out, int out_size, void* d_ws, size_t ws_size,
                              hipStream_t stream) {
  const float* x  = (const float*)d_in[0];
  const float* gw = (const float*)d_in[1];
  const float* w1 = (const float*)d_in[2];
  const float* w3 = (const float*)d_in[3];
  const float* w2 = (const float*)d_in[4];
  float* out = (float*)d_out;

  char* ws = (char*)d_ws;
  int*   counts  = (int*)(ws + 0);          // 8 ints
  int*   cursor  = (int*)(ws + 32);         // 8 ints
  int*   offsets = (int*)(ws + 64);         // 9 ints
  int*   top_i   = (int*)(ws + 1024);       // T*2
  float* top_w   = (float*)(ws + 17408);    // T*2
  int*   row_tok = (int*)(ws + 33792);      // 2T
  float* row_w   = (float*)(ws + 50176);    // 2T
  unsigned short* Xg   = (unsigned short*)(ws + 66560);              // 4096*1024 bf16
  unsigned short* hbuf = (unsigned short*)(ws + 66560 + 8388608);    // 4096*2048 bf16

  hipMemsetAsync(ws, 0, 128, stream);                               // counts+cursor
  hipMemsetAsync(d_out, 0, (size_t)out_size * sizeof(float), stream);

  router_kernel<<<T_TOK / 4, 256, 0, stream>>>(x, gw, counts, top_i, top_w);
  offsets_kernel<<<1, 64, 0, stream>>>(counts, offsets);
  scatter_kernel<<<(T_TOK + 255) / 256, 256, 0, stream>>>(top_i, top_w, offsets, cursor, row_tok, row_w);
  gather_kernel<<<T_TOK * 2, 256, 0, stream>>>(x, row_tok, Xg);
  gemm1_kernel<<<dim3(32, FFNDIM / 64, NEXP), 256, 0, stream>>>(Xg, w1, w3, counts, offsets, hbuf);
  gemm2_kernel<<<dim3(32, HID / 64, NEXP), 256, 0, stream>>>(hbuf, w2, counts, offsets, row_tok, row_w, out);
}

// Round 2
// 540.578 us; speedup vs baseline: 1.0311x; 1.0311x over previous
//
#include <hip/hip_runtime.h>
#include <hip/hip_bf16.h>

#define T_TOK 2048
#define HID 1024
#define FFNDIM 2048
#define NEXP 8
#define RPAD 128

typedef __attribute__((ext_vector_type(8))) short short8;
typedef __attribute__((ext_vector_type(4))) float f32x4;

__device__ inline unsigned short f2bf(float f) {
  union { float f; unsigned int u; } v; v.f = f;
  unsigned int u = v.u;
  unsigned int r = (u + 0x7fffu + ((u >> 16) & 1u)) >> 16;
  return (unsigned short)r;
}

__device__ inline void gload_lds16(const void* g, void* l) {
  __builtin_amdgcn_global_load_lds((const __attribute__((address_space(1))) void*)g,
                                   (__attribute__((address_space(3))) void*)l, 16, 0, 0);
}

// ---------------- router: 1 wave per token ----------------
__global__ __launch_bounds__(256) void router_kernel(
    const float* __restrict__ x, const float* __restrict__ gw,
    int* __restrict__ counts, int* __restrict__ top_i, float* __restrict__ top_w) {
  int lane = threadIdx.x & 63;
  int t = blockIdx.x * 4 + (threadIdx.x >> 6);
  if (t >= T_TOK) return;
  float xv[16];
#pragma unroll
  for (int i = 0; i < 16; ++i) xv[i] = x[(size_t)t * HID + i * 64 + lane];
  float logit[NEXP];
#pragma unroll
  for (int e = 0; e < NEXP; ++e) {
    float s = 0.f;
#pragma unroll
    for (int i = 0; i < 16; ++i) s += xv[i] * gw[e * HID + i * 64 + lane];
#pragma unroll
    for (int off = 32; off > 0; off >>= 1) s += __shfl_xor(s, off);
    logit[e] = s;
  }
  if (lane == 0) {
    float mx = logit[0];
#pragma unroll
    for (int e = 1; e < NEXP; ++e) mx = fmaxf(mx, logit[e]);
    float p[NEXP]; float sum = 0.f;
#pragma unroll
    for (int e = 0; e < NEXP; ++e) { p[e] = expf(logit[e] - mx); sum += p[e]; }
#pragma unroll
    for (int e = 0; e < NEXP; ++e) p[e] /= sum;
    int i0 = 0;
#pragma unroll
    for (int e = 1; e < NEXP; ++e) if (p[e] > p[i0]) i0 = e;
    int i1 = (i0 == 0) ? 1 : 0;
#pragma unroll
    for (int e = 0; e < NEXP; ++e) if (e != i0 && p[e] > p[i1]) i1 = e;
    float w0 = p[i0], w1v = p[i1];
    float s2 = w0 + w1v;
    w0 /= s2; w1v /= s2;
    top_i[t * 2 + 0] = i0; top_i[t * 2 + 1] = i1;
    top_w[t * 2 + 0] = w0; top_w[t * 2 + 1] = w1v;
    atomicAdd(&counts[i0], 1);
    atomicAdd(&counts[i1], 1);
  }
}

__global__ void offsets_kernel(const int* __restrict__ counts, int* __restrict__ offsets) {
  if (threadIdx.x == 0 && blockIdx.x == 0) {
    int s = 0;
    for (int e = 0; e < NEXP; ++e) { offsets[e] = s; s += counts[e]; }
    offsets[NEXP] = s;
  }
}

__global__ __launch_bounds__(256) void scatter_kernel(
    const int* __restrict__ top_i, const float* __restrict__ top_w,
    const int* __restrict__ offsets, int* __restrict__ cursor,
    int* __restrict__ row_tok, float* __restrict__ row_w) {
  int t = blockIdx.x * 256 + threadIdx.x;
  if (t >= T_TOK) return;
#pragma unroll
  for (int k = 0; k < 2; ++k) {
    int e = top_i[t * 2 + k];
    int p = atomicAdd(&cursor[e], 1);
    int idx = offsets[e] + p;
    row_tok[idx] = t;
    row_w[idx] = top_w[t * 2 + k];
  }
}

__global__ __launch_bounds__(256) void gather_kernel(
    const float* __restrict__ x, const int* __restrict__ row_tok,
    unsigned short* __restrict__ Xg) {
  int r = blockIdx.x;
  int t = row_tok[r];
  int c = threadIdx.x * 4;
  float4 v = *reinterpret_cast<const float4*>(x + (size_t)t * HID + c);
  ushort4 o;
  o.x = f2bf(v.x); o.y = f2bf(v.y); o.z = f2bf(v.z); o.w = f2bf(v.w);
  *reinterpret_cast<ushort4*>(Xg + (size_t)r * HID + c) = o;
}

// ---------------- fp32 -> bf16 weight conversion ----------------
__global__ __launch_bounds__(256) void w2bf_kernel(
    const float4* __restrict__ src, ushort4* __restrict__ dst, int n4) {
  int i = blockIdx.x * 256 + threadIdx.x;
  if (i >= n4) return;
  float4 v = src[i];
  ushort4 o;
  o.x = f2bf(v.x); o.y = f2bf(v.y); o.z = f2bf(v.z); o.w = f2bf(v.w);
  dst[i] = o;
}

// ---------------- GEMM1 big: 128x128 tile, global_load_lds, bf16 weights ----------------
__global__ __launch_bounds__(256, 1) void gemm1_big(
    const unsigned short* __restrict__ Xg,
    const unsigned short* __restrict__ Wb1, const unsigned short* __restrict__ Wb3,
    const int* __restrict__ counts, const int* __restrict__ offsets,
    unsigned short* __restrict__ hbuf) {
  int e = blockIdx.z;
  int cnt = counts[e];
  int mt = blockIdx.x, nt = blockIdx.y;
  if (mt * 128 >= cnt) return;
  int off = offsets[e];

  __shared__ alignas(16) unsigned short sA[128 * 32];
  __shared__ alignas(16) unsigned short sB1[128 * 32];
  __shared__ alignas(16) unsigned short sB3[128 * 32];

  int tid = threadIdx.x;
  int lane = tid & 63, wid = tid >> 6;
  int wm = wid >> 1, wn = wid & 1;
  int fr = lane & 15, fq = lane >> 4;

  // staging: 2 issues per 128x32 tile; issue i covers rows i*64 + wid*16 + lane/4
  int sk8 = (lane & 3) * 8;
  int r0 = wid * 16 + (lane >> 2);
  int r1 = 64 + r0;

  const unsigned short* aB  = Xg  + (size_t)(off + mt * 128) * HID;
  const unsigned short* b1B = Wb1 + (size_t)e * FFNDIM * HID + (size_t)(nt * 128) * HID;
  const unsigned short* b3B = Wb3 + (size_t)e * FFNDIM * HID + (size_t)(nt * 128) * HID;

  unsigned short* dA0 = &sA[wid * 512];
  unsigned short* dA1 = &sA[2048 + wid * 512];
  unsigned short* dB10 = &sB1[wid * 512];
  unsigned short* dB11 = &sB1[2048 + wid * 512];
  unsigned short* dB30 = &sB3[wid * 512];
  unsigned short* dB31 = &sB3[2048 + wid * 512];

  f32x4 acc1[4][4], acc3[4][4];
#pragma unroll
  for (int m = 0; m < 4; ++m)
#pragma unroll
    for (int n = 0; n < 4; ++n) {
      acc1[m][n] = (f32x4){0.f, 0.f, 0.f, 0.f};
      acc3[m][n] = (f32x4){0.f, 0.f, 0.f, 0.f};
    }

  for (int k0 = 0; k0 < HID; k0 += 32) {
    __syncthreads();
    gload_lds16(aB  + (size_t)r0 * HID + k0 + sk8, dA0);
    gload_lds16(aB  + (size_t)r1 * HID + k0 + sk8, dA1);
    gload_lds16(b1B + (size_t)r0 * HID + k0 + sk8, dB10);
    gload_lds16(b1B + (size_t)r1 * HID + k0 + sk8, dB11);
    gload_lds16(b3B + (size_t)r0 * HID + k0 + sk8, dB30);
    gload_lds16(b3B + (size_t)r1 * HID + k0 + sk8, dB31);
    __syncthreads();

    short8 a[4], f1[4], f3[4];
#pragma unroll
    for (int m = 0; m < 4; ++m)
      a[m] = *reinterpret_cast<const short8*>(&sA[(wm * 64 + m * 16 + fr) * 32 + fq * 8]);
#pragma unroll
    for (int n = 0; n < 4; ++n) {
      f1[n] = *reinterpret_cast<const short8*>(&sB1[(wn * 64 + n * 16 + fr) * 32 + fq * 8]);
      f3[n] = *reinterpret_cast<const short8*>(&sB3[(wn * 64 + n * 16 + fr) * 32 + fq * 8]);
    }
#pragma unroll
    for (int m = 0; m < 4; ++m)
#pragma unroll
      for (int n = 0; n < 4; ++n) {
        acc1[m][n] = __builtin_amdgcn_mfma_f32_16x16x32_bf16(a[m], f1[n], acc1[m][n], 0, 0, 0);
        acc3[m][n] = __builtin_amdgcn_mfma_f32_16x16x32_bf16(a[m], f3[n], acc3[m][n], 0, 0, 0);
      }
  }

#pragma unroll
  for (int m = 0; m < 4; ++m) {
    int rl = wm * 64 + m * 16 + fq * 4;
#pragma unroll
    for (int j = 0; j < 4; ++j) {
      int gm = mt * 128 + rl + j;
      if (gm < cnt) {
#pragma unroll
        for (int n = 0; n < 4; ++n) {
          float h1 = acc1[m][n][j], h3 = acc3[m][n][j];
          float sv = h1 / (1.f + expf(-h1)) * h3;
          int gn = nt * 128 + wn * 64 + n * 16 + fr;
          hbuf[(size_t)(off + gm) * FFNDIM + gn] = f2bf(sv);
        }
      }
    }
  }
}

// ---------------- GEMM2 big: out += rw * (h @ w2b^T) ----------------
__global__ __launch_bounds__(256, 2) void gemm2_big(
    const unsigned short* __restrict__ hbuf, const unsigned short* __restrict__ Wb2,
    const int* __restrict__ counts, const int* __restrict__ offsets,
    const int* __restrict__ row_tok, const float* __restrict__ row_w,
    float* __restrict__ out) {
  int e = blockIdx.z;
  int cnt = counts[e];
  int mt = blockIdx.x, nt = blockIdx.y;
  if (mt * 128 >= cnt) return;
  int off = offsets[e];

  __shared__ alignas(16) unsigned short sA[128 * 32];
  __shared__ alignas(16) unsigned short sB[128 * 32];

  int tid = threadIdx.x;
  int lane = tid & 63, wid = tid >> 6;
  int wm = wid >> 1, wn = wid & 1;
  int fr = lane & 15, fq = lane >> 4;

  int sk8 = (lane & 3) * 8;
  int r0 = wid * 16 + (lane >> 2);
  int r1 = 64 + r0;

  const unsigned short* aB = hbuf + (size_t)(off + mt * 128) * FFNDIM;
  const unsigned short* bB = Wb2 + (size_t)e * HID * FFNDIM + (size_t)(nt * 128) * FFNDIM;

  unsigned short* dA0 = &sA[wid * 512];
  unsigned short* dA1 = &sA[2048 + wid * 512];
  unsigned short* dB0 = &sB[wid * 512];
  unsigned short* dB1 = &sB[2048 + wid * 512];

  f32x4 acc[4][4];
#pragma unroll
  for (int m = 0; m < 4; ++m)
#pragma unroll
    for (int n = 0; n < 4; ++n) acc[m][n] = (f32x4){0.f, 0.f, 0.f, 0.f};

  for (int k0 = 0; k0 < FFNDIM; k0 += 32) {
    __syncthreads();
    gload_lds16(aB + (size_t)r0 * FFNDIM + k0 + sk8, dA0);
    gload_lds16(aB + (size_t)r1 * FFNDIM + k0 + sk8, dA1);
    gload_lds16(bB + (size_t)r0 * FFNDIM + k0 + sk8, dB0);
    gload_lds16(bB + (size_t)r1 * FFNDIM + k0 + sk8, dB1);
    __syncthreads();

    short8 a[4], b[4];
#pragma unroll
    for (int m = 0; m < 4; ++m)
      a[m] = *reinterpret_cast<const short8*>(&sA[(wm * 64 + m * 16 + fr) * 32 + fq * 8]);
#pragma unroll
    for (int n = 0; n < 4; ++n)
      b[n] = *reinterpret_cast<const short8*>(&sB[(wn * 64 + n * 16 + fr) * 32 + fq * 8]);
#pragma unroll
    for (int m = 0; m < 4; ++m)
#pragma unroll
      for (int n = 0; n < 4; ++n)
        acc[m][n] = __builtin_amdgcn_mfma_f32_16x16x32_bf16(a[m], b[n], acc[m][n], 0, 0, 0);
  }

#pragma unroll
  for (int m = 0; m < 4; ++m) {
    int rl = wm * 64 + m * 16 + fq * 4;
#pragma unroll
    for (int j = 0; j < 4; ++j) {
      int gm = mt * 128 + rl + j;
      if (gm < cnt) {
        int t = row_tok[off + gm];
        float rw = row_w[off + gm];
#pragma unroll
        for (int n = 0; n < 4; ++n) {
          int gn = nt * 128 + wn * 64 + n * 16 + fr;
          atomicAdd(&out[(size_t)t * HID + gn], acc[m][n][j] * rw);
        }
      }
    }
  }
}

// ================= fallback (round-1) small-tile fp32-staging GEMMs =================
__global__ __launch_bounds__(256) void gemm1_small(
    const unsigned short* __restrict__ Xg,
    const float* __restrict__ w1, const float* __restrict__ w3,
    const int* __restrict__ counts, const int* __restrict__ offsets,
    unsigned short* __restrict__ hbuf) {
  int e = blockIdx.z;
  int cnt = counts[e];
  int mt = blockIdx.x, nt = blockIdx.y;
  if (mt * 64 >= cnt) return;
  int off = offsets[e];
  __shared__ alignas(16) unsigned short sA[64 * 32];
  __shared__ alignas(16) unsigned short sB1[64 * 32];
  __shared__ alignas(16) unsigned short sB3[64 * 32];
  int tid = threadIdx.x;
  int lane = tid & 63, wid = tid >> 6;
  int wm = wid >> 1, wn = wid & 1;
  f32x4 acc1[2][2], acc3[2][2];
#pragma unroll
  for (int m = 0; m < 2; ++m)
#pragma unroll
    for (int n = 0; n < 2; ++n) {
      acc1[m][n] = (f32x4){0.f, 0.f, 0.f, 0.f};
      acc3[m][n] = (f32x4){0.f, 0.f, 0.f, 0.f};
    }
  int srow = tid >> 2;
  int skc = (tid & 3) * 8;
  int gmS = mt * 64 + srow;
  bool aval = gmS < cnt;
  const unsigned short* ap = Xg + (size_t)(off + (aval ? gmS : 0)) * HID + skc;
  const float* w1p = w1 + (size_t)e * FFNDIM * HID + (size_t)(nt * 64 + srow) * HID + skc;
  const float* w3p = w3 + (size_t)e * FFNDIM * HID + (size_t)(nt * 64 + srow) * HID + skc;
  int fr = lane & 15, fq = lane >> 4;
  for (int k0 = 0; k0 < HID; k0 += 32) {
    __syncthreads();
    short8 av = {0, 0, 0, 0, 0, 0, 0, 0};
    if (aval) av = *reinterpret_cast<const short8*>(ap + k0);
    *reinterpret_cast<short8*>(&sA[srow * 32 + skc]) = av;
    float4 b0 = *reinterpret_cast<const float4*>(w1p + k0);
    float4 b1 = *reinterpret_cast<const float4*>(w1p + k0 + 4);
    short8 bv;
    bv[0] = (short)f2bf(b0.x); bv[1] = (short)f2bf(b0.y);
    bv[2] = (short)f2bf(b0.z); bv[3] = (short)f2bf(b0.w);
    bv[4] = (short)f2bf(b1.x); bv[5] = (short)f2bf(b1.y);
    bv[6] = (short)f2bf(b1.z); bv[7] = (short)f2bf(b1.w);
    *reinterpret_cast<short8*>(&sB1[srow * 32 + skc]) = bv;
    float4 c0 = *reinterpret_cast<const float4*>(w3p + k0);
    float4 c1 = *reinterpret_cast<const float4*>(w3p + k0 + 4);
    short8 cv;
    cv[0] = (short)f2bf(c0.x); cv[1] = (short)f2bf(c0.y);
    cv[2] = (short)f2bf(c0.z); cv[3] = (short)f2bf(c0.w);
    cv[4] = (short)f2bf(c1.x); cv[5] = (short)f2bf(c1.y);
    cv[6] = (short)f2bf(c1.z); cv[7] = (short)f2bf(c1.w);
    *reinterpret_cast<short8*>(&sB3[srow * 32 + skc]) = cv;
    __syncthreads();
    short8 a[2], f1[2], f3[2];
#pragma unroll
    for (int m = 0; m < 2; ++m)
      a[m] = *reinterpret_cast<const short8*>(&sA[(wm * 32 + m * 16 + fr) * 32 + fq * 8]);
#pragma unroll
    for (int n = 0; n < 2; ++n) {
      f1[n] = *reinterpret_cast<const short8*>(&sB1[(wn * 32 + n * 16 + fr) * 32 + fq * 8]);
      f3[n] = *reinterpret_cast<const short8*>(&sB3[(wn * 32 + n * 16 + fr) * 32 + fq * 8]);
    }
#pragma unroll
    for (int m = 0; m < 2; ++m)
#pragma unroll
      for (int n = 0; n < 2; ++n) {
        acc1[m][n] = __builtin_amdgcn_mfma_f32_16x16x32_bf16(a[m], f1[n], acc1[m][n], 0, 0, 0);
        acc3[m][n] = __builtin_amdgcn_mfma_f32_16x16x32_bf16(a[m], f3[n], acc3[m][n], 0, 0, 0);
      }
  }
#pragma unroll
  for (int m = 0; m < 2; ++m) {
    int rl = wm * 32 + m * 16 + fq * 4;
#pragma unroll
    for (int j = 0; j < 4; ++j) {
      int gm = mt * 64 + rl + j;
      if (gm < cnt) {
#pragma unroll
        for (int n = 0; n < 2; ++n) {
          float h1 = acc1[m][n][j], h3 = acc3[m][n][j];
          float sv = h1 / (1.f + expf(-h1)) * h3;
          int gn = nt * 64 + wn * 32 + n * 16 + fr;
          hbuf[(size_t)(off + gm) * FFNDIM + gn] = f2bf(sv);
        }
      }
    }
  }
}

__global__ __launch_bounds__(256) void gemm2_small(
    const unsigned short* __restrict__ hbuf, const float* __restrict__ w2,
    const int* __restrict__ counts, const int* __restrict__ offsets,
    const int* __restrict__ row_tok, const float* __restrict__ row_w,
    float* __restrict__ out) {
  int e = blockIdx.z;
  int cnt = counts[e];
  int mt = blockIdx.x, nt = blockIdx.y;
  if (mt * 64 >= cnt) return;
  int off = offsets[e];
  __shared__ alignas(16) unsigned short sA[64 * 32];
  __shared__ alignas(16) unsigned short sB[64 * 32];
  int tid = threadIdx.x;
  int lane = tid & 63, wid = tid >> 6;
  int wm = wid >> 1, wn = wid & 1;
  f32x4 acc[2][2];
#pragma unroll
  for (int m = 0; m < 2; ++m)
#pragma unroll
    for (int n = 0; n < 2; ++n) acc[m][n] = (f32x4){0.f, 0.f, 0.f, 0.f};
  int srow = tid >> 2;
  int skc = (tid & 3) * 8;
  int gmS = mt * 64 + srow;
  bool aval = gmS < cnt;
  const unsigned short* ap = hbuf + (size_t)(off + (aval ? gmS : 0)) * FFNDIM + skc;
  const float* w2p = w2 + (size_t)e * HID * FFNDIM + (size_t)(nt * 64 + srow) * FFNDIM + skc;
  int fr = lane & 15, fq = lane >> 4;
  for (int k0 = 0; k0 < FFNDIM; k0 += 32) {
    __syncthreads();
    short8 av = {0, 0, 0, 0, 0, 0, 0, 0};
    if (aval) av = *reinterpret_cast<const short8*>(ap + k0);
    *reinterpret_cast<short8*>(&sA[srow * 32 + skc]) = av;
    float4 b0 = *reinterpret_cast<const float4*>(w2p + k0);
    float4 b1 = *reinterpret_cast<const float4*>(w2p + k0 + 4);
    short8 bv;
    bv[0] = (short)f2bf(b0.x); bv[1] = (short)f2bf(b0.y);
    bv[2] = (short)f2bf(b0.z); bv[3] = (short)f2bf(b0.w);
    bv[4] = (short)f2bf(b1.x); bv[5] = (short)f2bf(b1.y);
    bv[6] = (short)f2bf(b1.z); bv[7] = (short)f2bf(b1.w);
    *reinterpret_cast<short8*>(&sB[srow * 32 + skc]) = bv;
    __syncthreads();
    short8 a[2], b[2];
#pragma unroll
    for (int m = 0; m < 2; ++m)
      a[m] = *reinterpret_cast<const short8*>(&sA[(wm * 32 + m * 16 + fr) * 32 + fq * 8]);
#pragma unroll
    for (int n = 0; n < 2; ++n)
      b[n] = *reinterpret_cast<const short8*>(&sB[(wn * 32 + n * 16 + fr) * 32 + fq * 8]);
#pragma unroll
    for (int m = 0; m < 2; ++m)
#pragma unroll
      for (int n = 0; n < 2; ++n)
        acc[m][n] = __builtin_amdgcn_mfma_f32_16x16x32_bf16(a[m], b[n], acc[m][n], 0, 0, 0);
  }
#pragma unroll
  for (int m = 0; m < 2; ++m) {
    int rl = wm * 32 + m * 16 + fq * 4;
#pragma unroll
    for (int j = 0; j < 4; ++j) {
      int gm = mt * 64 + rl + j;
      if (gm < cnt) {
        int t = row_tok[off + gm];
        float rw = row_w[off + gm];
#pragma unroll
        for (int n = 0; n < 2; ++n) {
          int gn = nt * 64 + wn * 32 + n * 16 + fr;
          atomicAdd(&out[(size_t)t * HID + gn], acc[m][n][j] * rw);
        }
      }
    }
  }
}

extern "C" void kernel_launch(void* const* d_in, const int* in_sizes, int n_in,
                              void* d_out, int out_size, void* d_ws, size_t ws_size,
                              hipStream_t stream) {
  const float* x  = (const float*)d_in[0];
  const float* gw = (const float*)d_in[1];
  const float* w1 = (const float*)d_in[2];
  const float* w3 = (const float*)d_in[3];
  const float* w2 = (const float*)d_in[4];
  float* out = (float*)d_out;

  char* ws = (char*)d_ws;
  int*   counts  = (int*)(ws + 0);
  int*   cursor  = (int*)(ws + 32);
  int*   offsets = (int*)(ws + 64);
  int*   top_i   = (int*)(ws + 1024);
  float* top_w   = (float*)(ws + 17408);
  int*   row_tok = (int*)(ws + 33792);
  float* row_w   = (float*)(ws + 50176);
  unsigned short* Xg   = (unsigned short*)(ws + 66560);     // (4096+128)*1024 bf16
  unsigned short* hbuf = (unsigned short*)(ws + 8717312);   // (4096+128)*2048 bf16
  unsigned short* Wb1  = (unsigned short*)(ws + 26018816);  // 32 MB
  unsigned short* Wb3  = (unsigned short*)(ws + 59573248);  // 32 MB
  unsigned short* Wb2  = (unsigned short*)(ws + 93127680);  // 32 MB
  const size_t NEED = 126682112;

  hipMemsetAsync(ws, 0, 128, stream);
  hipMemsetAsync(d_out, 0, (size_t)out_size * sizeof(float), stream);

  router_kernel<<<T_TOK / 4, 256, 0, stream>>>(x, gw, counts, top_i, top_w);
  offsets_kernel<<<1, 64, 0, stream>>>(counts, offsets);
  scatter_kernel<<<(T_TOK + 255) / 256, 256, 0, stream>>>(top_i, top_w, offsets, cursor, row_tok, row_w);
  gather_kernel<<<T_TOK * 2, 256, 0, stream>>>(x, row_tok, Xg);

  if (ws_size >= NEED) {
    const int n4 = NEXP * FFNDIM * HID / 4;  // 4,194,304 float4 per tensor
    w2bf_kernel<<<n4 / 256, 256, 0, stream>>>((const float4*)w1, (ushort4*)Wb1, n4);
    w2bf_kernel<<<n4 / 256, 256, 0, stream>>>((const float4*)w3, (ushort4*)Wb3, n4);
    w2bf_kernel<<<n4 / 256, 256, 0, stream>>>((const float4*)w2, (ushort4*)Wb2, n4);
    gemm1_big<<<dim3(16, FFNDIM / 128, NEXP), 256, 0, stream>>>(Xg, Wb1, Wb3, counts, offsets, hbuf);
    gemm2_big<<<dim3(16, HID / 128, NEXP), 256, 0, stream>>>(hbuf, Wb2, counts, offsets, row_tok, row_w, out);
  } else {
    gemm1_small<<<dim3(32, FFNDIM / 64, NEXP), 256, 0, stream>>>(Xg, w1, w3, counts, offsets, hbuf);
    gemm2_small<<<dim3(32, HID / 64, NEXP), 256, 0, stream>>>(hbuf, w2, counts, offsets, row_tok, row_w, out);
  }
}

// Round 3
// 278.865 us; speedup vs baseline: 1.9989x; 1.9385x over previous
//
#include <hip/hip_runtime.h>
#include <hip/hip_bf16.h>

#define T_TOK 2048
#define HID 1024
#define FFNDIM 2048
#define NEXP 8

typedef __attribute__((ext_vector_type(8))) short short8;
typedef __attribute__((ext_vector_type(4))) float f32x4;

__device__ inline unsigned short f2bf(float f) {
  union { float f; unsigned int u; } v; v.f = f;
  unsigned int u = v.u;
  unsigned int r = (u + 0x7fffu + ((u >> 16) & 1u)) >> 16;
  return (unsigned short)r;
}

__device__ inline void gload_lds16(const void* g, void* l) {
  __builtin_amdgcn_global_load_lds((const __attribute__((address_space(1))) void*)g,
                                   (__attribute__((address_space(3))) void*)l, 16, 0, 0);
}

// ---------------- router: 1 wave per token ----------------
__global__ __launch_bounds__(256) void router_kernel(
    const float* __restrict__ x, const float* __restrict__ gw,
    int* __restrict__ counts, int* __restrict__ top_i, float* __restrict__ top_w) {
  int lane = threadIdx.x & 63;
  int t = blockIdx.x * 4 + (threadIdx.x >> 6);
  if (t >= T_TOK) return;
  float xv[16];
#pragma unroll
  for (int i = 0; i < 16; ++i) xv[i] = x[(size_t)t * HID + i * 64 + lane];
  float logit[NEXP];
#pragma unroll
  for (int e = 0; e < NEXP; ++e) {
    float s = 0.f;
#pragma unroll
    for (int i = 0; i < 16; ++i) s += xv[i] * gw[e * HID + i * 64 + lane];
#pragma unroll
    for (int off = 32; off > 0; off >>= 1) s += __shfl_xor(s, off);
    logit[e] = s;
  }
  if (lane == 0) {
    float mx = logit[0];
#pragma unroll
    for (int e = 1; e < NEXP; ++e) mx = fmaxf(mx, logit[e]);
    float p[NEXP]; float sum = 0.f;
#pragma unroll
    for (int e = 0; e < NEXP; ++e) { p[e] = expf(logit[e] - mx); sum += p[e]; }
#pragma unroll
    for (int e = 0; e < NEXP; ++e) p[e] /= sum;
    int i0 = 0;
#pragma unroll
    for (int e = 1; e < NEXP; ++e) if (p[e] > p[i0]) i0 = e;
    int i1 = (i0 == 0) ? 1 : 0;
#pragma unroll
    for (int e = 0; e < NEXP; ++e) if (e != i0 && p[e] > p[i1]) i1 = e;
    float w0 = p[i0], w1v = p[i1];
    float s2 = w0 + w1v;
    w0 /= s2; w1v /= s2;
    top_i[t * 2 + 0] = i0; top_i[t * 2 + 1] = i1;
    top_w[t * 2 + 0] = w0; top_w[t * 2 + 1] = w1v;
    atomicAdd(&counts[i0], 1);
    atomicAdd(&counts[i1], 1);
  }
}

__global__ void offsets_kernel(const int* __restrict__ counts, int* __restrict__ offsets) {
  if (threadIdx.x == 0 && blockIdx.x == 0) {
    int s = 0;
    for (int e = 0; e < NEXP; ++e) { offsets[e] = s; s += counts[e]; }
    offsets[NEXP] = s;
  }
}

__global__ __launch_bounds__(256) void scatter_kernel(
    const int* __restrict__ top_i, const float* __restrict__ top_w,
    const int* __restrict__ offsets, int* __restrict__ cursor,
    int* __restrict__ row_tok, float* __restrict__ row_w) {
  int t = blockIdx.x * 256 + threadIdx.x;
  if (t >= T_TOK) return;
#pragma unroll
  for (int k = 0; k < 2; ++k) {
    int e = top_i[t * 2 + k];
    int p = atomicAdd(&cursor[e], 1);
    int idx = offsets[e] + p;
    row_tok[idx] = t;
    row_w[idx] = top_w[t * 2 + k];
  }
}

__global__ __launch_bounds__(256) void gather_kernel(
    const float* __restrict__ x, const int* __restrict__ row_tok,
    unsigned short* __restrict__ Xg) {
  int r = blockIdx.x;
  int t = row_tok[r];
  int c = threadIdx.x * 4;
  float4 v = *reinterpret_cast<const float4*>(x + (size_t)t * HID + c);
  ushort4 o;
  o.x = f2bf(v.x); o.y = f2bf(v.y); o.z = f2bf(v.z); o.w = f2bf(v.w);
  *reinterpret_cast<ushort4*>(Xg + (size_t)r * HID + c) = o;
}

// ---------------- fp32 -> bf16 conversion for all 3 weight tensors ----------------
__global__ __launch_bounds__(256) void w2bf3_kernel(
    const float4* __restrict__ s0, const float4* __restrict__ s1, const float4* __restrict__ s2,
    ushort4* __restrict__ d0, ushort4* __restrict__ d1, ushort4* __restrict__ d2, int n4) {
  int i = blockIdx.x * 256 + threadIdx.x;
  if (i >= n4) return;
  const float4* s = (blockIdx.y == 0) ? s0 : (blockIdx.y == 1) ? s1 : s2;
  ushort4* d = (blockIdx.y == 0) ? d0 : (blockIdx.y == 1) ? d1 : d2;
  float4 v = s[i];
  ushort4 o;
  o.x = f2bf(v.x); o.y = f2bf(v.y); o.z = f2bf(v.z); o.w = f2bf(v.w);
  d[i] = o;
}

// ---- staging helpers: linear LDS dest + pre-swizzled global source (rule #21) ----
// LDS tile layout [128][32] shorts; element (row, colblock cb) stored at slot cb^(row&3).
__device__ inline void stage_tile(const unsigned short* gbase, unsigned short* lbase,
                                  int wid, size_t rowoff) {
  // rowoff = (wid*16 + rsub)*LDK + k0 + csw  precomputed by caller? cheaper: caller passes full src
  gload_lds16(gbase, lbase);
}

// ---------------- GEMM1: 128x128 tile, BK=32, double-buffered, swizzled ----------------
__global__ __launch_bounds__(256, 2) void gemm1_db(
    const unsigned short* __restrict__ Xg,
    const unsigned short* __restrict__ Wb1, const unsigned short* __restrict__ Wb3,
    const int* __restrict__ counts, const int* __restrict__ offsets,
    unsigned short* __restrict__ hbuf) {
  int e = blockIdx.z;
  int cnt = counts[e];
  int nt = blockIdx.x, mt = blockIdx.y;
  if (mt * 128 >= cnt) return;
  int off = offsets[e];

  __shared__ alignas(16) unsigned short sA[2][128 * 32];
  __shared__ alignas(16) unsigned short sB1[2][128 * 32];
  __shared__ alignas(16) unsigned short sB3[2][128 * 32];

  int tid = threadIdx.x;
  int lane = tid & 63, wid = tid >> 6;
  int wm = wid >> 1, wn = wid & 1;
  int fr = lane & 15, fq = lane >> 4;

  // staging geometry: each wave stages rows [h*64 + wid*16, +16) of each tile
  int rsub = lane >> 2;                              // 0..15
  int csw = (((lane & 3) ^ (rsub & 3)) << 3);        // swizzled col (elements)
  size_t ro0 = (size_t)(wid * 16 + rsub) * HID + csw;
  size_t ro1 = ro0 + (size_t)64 * HID;
  int ld0 = (wid * 16) * 32;                         // LDS base (shorts), half 0
  int ld1 = (64 + wid * 16) * 32;

  const unsigned short* aB  = Xg  + (size_t)(off + mt * 128) * HID;
  const unsigned short* b1B = Wb1 + (size_t)e * FFNDIM * HID + (size_t)(nt * 128) * HID;
  const unsigned short* b3B = Wb3 + (size_t)e * FFNDIM * HID + (size_t)(nt * 128) * HID;

  f32x4 acc1[4][4], acc3[4][4];
#pragma unroll
  for (int m = 0; m < 4; ++m)
#pragma unroll
    for (int n = 0; n < 4; ++n) {
      acc1[m][n] = (f32x4){0.f, 0.f, 0.f, 0.f};
      acc3[m][n] = (f32x4){0.f, 0.f, 0.f, 0.f};
    }

#define STAGE1(P, K0)                                           \
  do {                                                          \
    gload_lds16(aB  + ro0 + (K0), &sA[P][ld0]);                 \
    gload_lds16(aB  + ro1 + (K0), &sA[P][ld1]);                 \
    gload_lds16(b1B + ro0 + (K0), &sB1[P][ld0]);                \
    gload_lds16(b1B + ro1 + (K0), &sB1[P][ld1]);                \
    gload_lds16(b3B + ro0 + (K0), &sB3[P][ld0]);                \
    gload_lds16(b3B + ro1 + (K0), &sB3[P][ld1]);                \
  } while (0)

  int sl = ((fq ^ (fr & 3)) << 3);   // swizzled slot offset (elements) for reads

#define COMP1(P)                                                                  \
  do {                                                                            \
    short8 a[4], f1[4], f3[4];                                                    \
    _Pragma("unroll")                                                             \
    for (int m = 0; m < 4; ++m)                                                   \
      a[m] = *reinterpret_cast<const short8*>(&sA[P][(wm * 64 + m * 16 + fr) * 32 + sl]); \
    _Pragma("unroll")                                                             \
    for (int n = 0; n < 4; ++n) {                                                 \
      f1[n] = *reinterpret_cast<const short8*>(&sB1[P][(wn * 64 + n * 16 + fr) * 32 + sl]); \
      f3[n] = *reinterpret_cast<const short8*>(&sB3[P][(wn * 64 + n * 16 + fr) * 32 + sl]); \
    }                                                                             \
    _Pragma("unroll")                                                             \
    for (int m = 0; m < 4; ++m)                                                   \
      _Pragma("unroll")                                                           \
      for (int n = 0; n < 4; ++n) {                                               \
        acc1[m][n] = __builtin_amdgcn_mfma_f32_16x16x32_bf16(a[m], f1[n], acc1[m][n], 0, 0, 0); \
        acc3[m][n] = __builtin_amdgcn_mfma_f32_16x16x32_bf16(a[m], f3[n], acc3[m][n], 0, 0, 0); \
      }                                                                           \
  } while (0)

  STAGE1(0, 0);
  __syncthreads();
  for (int t = 0; t < 32; t += 2) {
    STAGE1(1, (t + 1) * 32);      // issue next-tile loads BEFORE compute
    COMP1(0);
    __syncthreads();              // drains vmcnt (buf1 landed) + all waves done with buf0
    if (t + 2 < 32) STAGE1(0, (t + 2) * 32);
    COMP1(1);
    __syncthreads();
  }

#pragma unroll
  for (int m = 0; m < 4; ++m) {
    int rl = wm * 64 + m * 16 + fq * 4;
#pragma unroll
    for (int j = 0; j < 4; ++j) {
      int gm = mt * 128 + rl + j;
      if (gm < cnt) {
#pragma unroll
        for (int n = 0; n < 4; ++n) {
          float h1 = acc1[m][n][j], h3 = acc3[m][n][j];
          float sv = h1 / (1.f + expf(-h1)) * h3;
          int gn = nt * 128 + wn * 64 + n * 16 + fr;
          hbuf[(size_t)(off + gm) * FFNDIM + gn] = f2bf(sv);
        }
      }
    }
  }
#undef STAGE1
#undef COMP1
}

// ---------------- GEMM2: 128x128 tile, BK=32, split-K=2, double-buffered ----------------
__global__ __launch_bounds__(256, 2) void gemm2_db(
    const unsigned short* __restrict__ hbuf, const unsigned short* __restrict__ Wb2,
    const int* __restrict__ counts, const int* __restrict__ offsets,
    const int* __restrict__ row_tok, const float* __restrict__ row_w,
    float* __restrict__ out) {
  int zz = blockIdx.z;
  int e = zz & 7, kz = zz >> 3;
  int cnt = counts[e];
  int nt = blockIdx.x, mt = blockIdx.y;
  if (mt * 128 >= cnt) return;
  int off = offsets[e];
  int kbase = kz * (FFNDIM / 2);

  __shared__ alignas(16) unsigned short sA[2][128 * 32];
  __shared__ alignas(16) unsigned short sB[2][128 * 32];

  int tid = threadIdx.x;
  int lane = tid & 63, wid = tid >> 6;
  int wm = wid >> 1, wn = wid & 1;
  int fr = lane & 15, fq = lane >> 4;

  int rsub = lane >> 2;
  int csw = (((lane & 3) ^ (rsub & 3)) << 3);
  size_t ro0 = (size_t)(wid * 16 + rsub) * FFNDIM + kbase + csw;
  size_t ro1 = ro0 + (size_t)64 * FFNDIM;
  int ld0 = (wid * 16) * 32;
  int ld1 = (64 + wid * 16) * 32;

  const unsigned short* aB = hbuf + (size_t)(off + mt * 128) * FFNDIM;
  const unsigned short* bB = Wb2 + (size_t)e * HID * FFNDIM + (size_t)(nt * 128) * FFNDIM;

  f32x4 acc[4][4];
#pragma unroll
  for (int m = 0; m < 4; ++m)
#pragma unroll
    for (int n = 0; n < 4; ++n) acc[m][n] = (f32x4){0.f, 0.f, 0.f, 0.f};

#define STAGE2(P, K0)                                           \
  do {                                                          \
    gload_lds16(aB + ro0 + (K0), &sA[P][ld0]);                  \
    gload_lds16(aB + ro1 + (K0), &sA[P][ld1]);                  \
    gload_lds16(bB + ro0 + (K0), &sB[P][ld0]);                  \
    gload_lds16(bB + ro1 + (K0), &sB[P][ld1]);                  \
  } while (0)

  int sl = ((fq ^ (fr & 3)) << 3);

#define COMP2(P)                                                                  \
  do {                                                                            \
    short8 a[4], b[4];                                                            \
    _Pragma("unroll")                                                             \
    for (int m = 0; m < 4; ++m)                                                   \
      a[m] = *reinterpret_cast<const short8*>(&sA[P][(wm * 64 + m * 16 + fr) * 32 + sl]); \
    _Pragma("unroll")                                                             \
    for (int n = 0; n < 4; ++n)                                                   \
      b[n] = *reinterpret_cast<const short8*>(&sB[P][(wn * 64 + n * 16 + fr) * 32 + sl]); \
    _Pragma("unroll")                                                             \
    for (int m = 0; m < 4; ++m)                                                   \
      _Pragma("unroll")                                                           \
      for (int n = 0; n < 4; ++n)                                                 \
        acc[m][n] = __builtin_amdgcn_mfma_f32_16x16x32_bf16(a[m], b[n], acc[m][n], 0, 0, 0); \
  } while (0)

  STAGE2(0, 0);
  __syncthreads();
  for (int t = 0; t < 32; t += 2) {
    STAGE2(1, (t + 1) * 32);
    COMP2(0);
    __syncthreads();
    if (t + 2 < 32) STAGE2(0, (t + 2) * 32);
    COMP2(1);
    __syncthreads();
  }

#pragma unroll
  for (int m = 0; m < 4; ++m) {
    int rl = wm * 64 + m * 16 + fq * 4;
#pragma unroll
    for (int j = 0; j < 4; ++j) {
      int gm = mt * 128 + rl + j;
      if (gm < cnt) {
        int t = row_tok[off + gm];
        float rw = row_w[off + gm];
#pragma unroll
        for (int n = 0; n < 4; ++n) {
          int gn = nt * 128 + wn * 64 + n * 16 + fr;
          atomicAdd(&out[(size_t)t * HID + gn], acc[m][n][j] * rw);
        }
      }
    }
  }
#undef STAGE2
#undef COMP2
}

extern "C" void kernel_launch(void* const* d_in, const int* in_sizes, int n_in,
                              void* d_out, int out_size, void* d_ws, size_t ws_size,
                              hipStream_t stream) {
  const float* x  = (const float*)d_in[0];
  const float* gw = (const float*)d_in[1];
  const float* w1 = (const float*)d_in[2];
  const float* w3 = (const float*)d_in[3];
  const float* w2 = (const float*)d_in[4];
  float* out = (float*)d_out;

  char* ws = (char*)d_ws;
  int*   counts  = (int*)(ws + 0);
  int*   cursor  = (int*)(ws + 32);
  int*   offsets = (int*)(ws + 64);
  int*   top_i   = (int*)(ws + 1024);
  float* top_w   = (float*)(ws + 17408);
  int*   row_tok = (int*)(ws + 33792);
  float* row_w   = (float*)(ws + 50176);
  unsigned short* Xg   = (unsigned short*)(ws + 66560);     // (4096+128)*1024 bf16
  unsigned short* hbuf = (unsigned short*)(ws + 8717312);   // (4096+128)*2048 bf16
  unsigned short* Wb1  = (unsigned short*)(ws + 26018816);  // 32 MB
  unsigned short* Wb3  = (unsigned short*)(ws + 59573248);  // 32 MB
  unsigned short* Wb2  = (unsigned short*)(ws + 93127680);  // 32 MB

  hipMemsetAsync(ws, 0, 128, stream);
  hipMemsetAsync(d_out, 0, (size_t)out_size * sizeof(float), stream);

  router_kernel<<<T_TOK / 4, 256, 0, stream>>>(x, gw, counts, top_i, top_w);
  offsets_kernel<<<1, 64, 0, stream>>>(counts, offsets);
  scatter_kernel<<<(T_TOK + 255) / 256, 256, 0, stream>>>(top_i, top_w, offsets, cursor, row_tok, row_w);
  gather_kernel<<<T_TOK * 2, 256, 0, stream>>>(x, row_tok, Xg);

  const int n4 = NEXP * FFNDIM * HID / 4;  // 4,194,304 float4 per tensor
  w2bf3_kernel<<<dim3(n4 / 256, 3), 256, 0, stream>>>(
      (const float4*)w1, (const float4*)w3, (const float4*)w2,
      (ushort4*)Wb1, (ushort4*)Wb3, (ushort4*)Wb2, n4);

  // grid: nt fastest (fully active) -> active blocks contiguous -> XCD-balanced
  gemm1_db<<<dim3(FFNDIM / 128, 16, NEXP), 256, 0, stream>>>(Xg, Wb1, Wb3, counts, offsets, hbuf);
  gemm2_db<<<dim3(HID / 128, 16, NEXP * 2), 256, 0, stream>>>(hbuf, Wb2, counts, offsets, row_tok, row_w, out);
}